// Round 1
// baseline (272.305 us; speedup 1.0000x reference)
//
#include <hip/hip_runtime.h>
#include <stdint.h>

typedef unsigned short u16;
typedef __attribute__((ext_vector_type(8))) short short8;
typedef __attribute__((ext_vector_type(4))) float f32x4;

#define MFMA16(a, b, c) __builtin_amdgcn_mfma_f32_16x16x32_bf16(a, b, c, 0, 0, 0)

__device__ __forceinline__ void async16(void* lds, const void* g) {
  __builtin_amdgcn_global_load_lds(
      (const __attribute__((address_space(1))) void*)g,
      (__attribute__((address_space(3))) void*)lds, 16, 0, 0);
}

__device__ __forceinline__ u16 f2bf(float f) {
  unsigned u = __float_as_uint(f);
  u += 0x7FFF + ((u >> 16) & 1);
  return (u16)(u >> 16);
}

// ---------------- fp32 -> bf16 conversion ----------------
__global__ void convert_kernel(const float* __restrict__ src, u16* __restrict__ dst, int n4) {
  int i = blockIdx.x * 256 + threadIdx.x;
  if (i >= n4) return;
  float4 v = ((const float4*)src)[i];
  u16 o0 = f2bf(v.x), o1 = f2bf(v.y), o2 = f2bf(v.z), o3 = f2bf(v.w);
  unsigned lo = (unsigned)o0 | ((unsigned)o1 << 16);
  unsigned hi = (unsigned)o2 | ((unsigned)o3 << 16);
  ((uint2*)dst)[i] = make_uint2(lo, hi);
}

// ---------------- GEMM: C[m,n] = sum_k A[m,k] * Bw[n,k]  (both bf16, K=768) ----
// MODE 0: N=2304 (QKV fused), scatter bf16 into Q/K/V [48][2048][64]
// MODE 1: N=768, plain fp32 row-major output
template <int MODE>
__global__ __launch_bounds__(256) void gemm_bt(const u16* __restrict__ A,
                                               const u16* __restrict__ Bw,
                                               u16* __restrict__ Qb, u16* __restrict__ Kb,
                                               u16* __restrict__ Vb, float* __restrict__ Out) {
  __shared__ __align__(16) u16 As[128 * 32];
  __shared__ __align__(16) u16 Bs[128 * 32];
  const int bm = blockIdx.x & 63;   // 64 M-tiles
  const int bn = blockIdx.x >> 6;
  const int tid = threadIdx.x;
  const int wave = tid >> 6, lane = tid & 63;
  const int arow = lane & 15, kg = lane >> 4;
  const int wr = wave >> 1, wc = wave & 1;

  const int o = tid * 16;
  const int rowS = o >> 6;     // 64B rows (BK=32 bf16)
  const int cbS = o & 63;
  const char* gA0 = (const char*)A + (size_t)(bm * 128 + rowS) * 1536 + cbS;
  const char* gA1 = gA0 + (size_t)64 * 1536;
  const char* gB0 = (const char*)Bw + (size_t)(bn * 128 + rowS) * 1536 + cbS;
  const char* gB1 = gB0 + (size_t)64 * 1536;
  char* lA = (char*)As + wave * 1024;
  char* lB = (char*)Bs + wave * 1024;

  f32x4 acc[4][4];
#pragma unroll
  for (int m = 0; m < 4; ++m)
#pragma unroll
    for (int n = 0; n < 4; ++n) acc[m][n] = (f32x4)(0.0f);

  for (int kk = 0; kk < 24; ++kk) {
    async16(lA, gA0);
    async16(lA + 4096, gA1);
    async16(lB, gB0);
    async16(lB + 4096, gB1);
    gA0 += 64; gA1 += 64; gB0 += 64; gB1 += 64;
    __syncthreads();
    short8 av[4], bv[4];
#pragma unroll
    for (int m = 0; m < 4; ++m)
      av[m] = *(const short8*)(As + (wr * 64 + m * 16 + arow) * 32 + kg * 8);
#pragma unroll
    for (int n = 0; n < 4; ++n)
      bv[n] = *(const short8*)(Bs + (wc * 64 + n * 16 + arow) * 32 + kg * 8);
#pragma unroll
    for (int m = 0; m < 4; ++m)
#pragma unroll
      for (int n = 0; n < 4; ++n) acc[m][n] = MFMA16(av[m], bv[n], acc[m][n]);
    __syncthreads();
  }

#pragma unroll
  for (int m = 0; m < 4; ++m) {
    const int rbase = bm * 128 + wr * 64 + m * 16 + kg * 4;
#pragma unroll
    for (int n = 0; n < 4; ++n) {
      const int c = bn * 128 + wc * 64 + n * 16 + arow;
#pragma unroll
      for (int i = 0; i < 4; ++i) {
        float v = acc[m][n][i];
        int rr = rbase + i;
        if (MODE == 0) {
          int which = c / 768;
          int hc = c - which * 768;
          int h = hc >> 6, d = hc & 63;
          int b = rr >> 11, s = rr & 2047;
          u16* dst = (which == 0) ? Qb : ((which == 1) ? Kb : Vb);
          dst[((size_t)(b * 12 + h) * 2048 + s) * 64 + d] = f2bf(v);
        } else {
          Out[(size_t)rr * 768 + c] = v;
        }
      }
    }
  }
}

// ---------------- causal flash attention ----------------
// grid: 48 head-batches * 32 Q-tiles; block 256 (4 waves, 16 q-rows each)
__global__ __launch_bounds__(256) void attn_kernel(const u16* __restrict__ Qb,
                                                   const u16* __restrict__ Kb,
                                                   const u16* __restrict__ Vb,
                                                   u16* __restrict__ AOb) {
  __shared__ __align__(16) u16 Ks[64 * 64];   // K tile, XOR-swizzled rows (128B)
  __shared__ __align__(16) u16 Vt[64 * 64];   // V^T tile [d][k], XOR-swizzled
  __shared__ __align__(16) u16 Ps[4][16 * 64];  // per-wave P, XOR-swizzled

  const int bid = blockIdx.x;
  const int qt = bid & 31, bh = bid >> 5;
  const int tid = threadIdx.x, wave = tid >> 6, lane = tid & 63;
  const int arow = lane & 15, kg = lane >> 4;
  const size_t hbase = (size_t)bh * (2048 * 64);
  const u16* Qh = Qb + hbase;
  const u16* Kh = Kb + hbase;
  const u16* Vh = Vb + hbase;
  const int q0 = qt * 64 + wave * 16;

  short8 qf[2];
#pragma unroll
  for (int ks = 0; ks < 2; ++ks)
    qf[ks] = *(const short8*)(Qh + (size_t)(q0 + arow) * 64 + ks * 32 + kg * 8);

  f32x4 o_acc[4];
  float mrow[4], lrow[4];
#pragma unroll
  for (int n = 0; n < 4; ++n) o_acc[n] = (f32x4)(0.0f);
#pragma unroll
  for (int i = 0; i < 4; ++i) { mrow[i] = -1e30f; lrow[i] = 0.0f; }

  const int o0 = tid * 16;
  const int krow0 = o0 >> 7, kcb0 = o0 & 127;   // 128B rows
  const int krow1 = krow0 + 32;
  char* lK = (char*)Ks + wave * 1024;
  const int sw0 = kcb0 ^ (((krow0 ^ (krow0 >> 3)) & 7) << 4);
  const int sw1 = kcb0 ^ (((krow1 ^ (krow1 >> 3)) & 7) << 4);

  const int ktiles = qt + 1;
  for (int kt = 0; kt < ktiles; ++kt) {
    // stage K: linear LDS dest + inverse-swizzled global source (G21)
    {
      const char* base = (const char*)(Kh + (size_t)kt * 4096);
      async16(lK, base + krow0 * 128 + sw0);
      async16(lK + 4096, base + krow1 * 128 + sw1);
    }
    // stage V transposed (reg-staged), swizzled writes
#pragma unroll
    for (int it = 0; it < 2; ++it) {
      int oo = o0 + it * 4096;
      int kr = oo >> 7, d0 = (oo & 127) >> 1;
      uint4 raw = *(const uint4*)((const char*)(Vh + (size_t)kt * 4096) + kr * 128 + d0 * 2);
      unsigned wds[4] = {raw.x, raw.y, raw.z, raw.w};
#pragma unroll
      for (int j = 0; j < 8; ++j) {
        int d = d0 + j;
        u16 val = (u16)(wds[j >> 1] >> ((j & 1) * 16));
        int off = (d << 7) + ((kr * 2) ^ (((d ^ (d >> 3)) & 7) << 4));
        *(u16*)((char*)Vt + off) = val;
      }
    }
    __syncthreads();

    // QK^T: S[q][kcol], A=Q frag, B=K rows (contiguous in d)
    f32x4 s_acc[4];
#pragma unroll
    for (int cg = 0; cg < 4; ++cg) s_acc[cg] = (f32x4)(0.0f);
#pragma unroll
    for (int cg = 0; cg < 4; ++cg) {
      int krow = cg * 16 + arow;
      int fsw = ((krow ^ (krow >> 3)) & 7) << 4;
#pragma unroll
      for (int ks = 0; ks < 2; ++ks) {
        short8 kf = *(const short8*)((char*)Ks + (krow << 7) + ((ks * 64 + kg * 16) ^ fsw));
        s_acc[cg] = MFMA16(qf[ks], kf, s_acc[cg]);
      }
    }

    // online softmax (wave-parallel: rows spread over i, cols over 16 lanes)
    const int kbase = kt * 64;
    float sv[4][4];
#pragma unroll
    for (int cg = 0; cg < 4; ++cg) {
      int kc = kbase + cg * 16 + arow;
#pragma unroll
      for (int i = 0; i < 4; ++i) {
        float s = s_acc[cg][i] * 0.125f;
        int qr = q0 + kg * 4 + i;
        sv[cg][i] = (kc > qr) ? -1e30f : s;
      }
    }
    float rmax[4];
#pragma unroll
    for (int i = 0; i < 4; ++i)
      rmax[i] = fmaxf(fmaxf(sv[0][i], sv[1][i]), fmaxf(sv[2][i], sv[3][i]));
#pragma unroll
    for (int off = 1; off < 16; off <<= 1)
#pragma unroll
      for (int i = 0; i < 4; ++i) rmax[i] = fmaxf(rmax[i], __shfl_xor(rmax[i], off));

    float corr[4];
#pragma unroll
    for (int i = 0; i < 4; ++i) {
      float mnew = fmaxf(mrow[i], rmax[i]);
      corr[i] = __expf(mrow[i] - mnew);
      mrow[i] = mnew;
    }
    float pvv[4][4];
    float rsum[4] = {0.f, 0.f, 0.f, 0.f};
#pragma unroll
    for (int cg = 0; cg < 4; ++cg)
#pragma unroll
      for (int i = 0; i < 4; ++i) {
        float p = __expf(sv[cg][i] - mrow[i]);
        pvv[cg][i] = p;
        rsum[i] += p;
      }
#pragma unroll
    for (int off = 1; off < 16; off <<= 1)
#pragma unroll
      for (int i = 0; i < 4; ++i) rsum[i] += __shfl_xor(rsum[i], off);
#pragma unroll
    for (int i = 0; i < 4; ++i) lrow[i] = lrow[i] * corr[i] + rsum[i];
#pragma unroll
    for (int n = 0; n < 4; ++n)
#pragma unroll
      for (int i = 0; i < 4; ++i) o_acc[n][i] *= corr[i];

    // write P (bf16) to per-wave LDS, swizzled
    u16* Pw = &Ps[wave][0];
#pragma unroll
    for (int cg = 0; cg < 4; ++cg)
#pragma unroll
      for (int i = 0; i < 4; ++i) {
        int r = kg * 4 + i;
        int off = (r << 7) + (((cg * 16 + arow) * 2) ^ (((r ^ (r >> 3)) & 7) << 4));
        *(u16*)((char*)Pw + off) = f2bf(pvv[cg][i]);
      }

    // PV: A = P [16q x 64k], B = V^T rows (contiguous in k)
#pragma unroll
    for (int ks = 0; ks < 2; ++ks) {
      int aoff = (arow << 7) + (((ks * 32 + kg * 8) * 2) ^ (((arow ^ (arow >> 3)) & 7) << 4));
      short8 pa = *(const short8*)((char*)Pw + aoff);
#pragma unroll
      for (int n = 0; n < 4; ++n) {
        int vrow = n * 16 + arow;
        int boff = (vrow << 7) + ((ks * 64 + kg * 16) ^ (((vrow ^ (vrow >> 3)) & 7) << 4));
        short8 vb = *(const short8*)((char*)Vt + boff);
        o_acc[n] = MFMA16(pa, vb, o_acc[n]);
      }
    }
    __syncthreads();
  }

  // epilogue: normalize and store attn_out bf16 in [B][S][H*64] layout
  const int b = bh / 12, h = bh - b * 12;
#pragma unroll
  for (int n = 0; n < 4; ++n)
#pragma unroll
    for (int i = 0; i < 4; ++i) {
      int qr = q0 + kg * 4 + i;
      int d = n * 16 + arow;
      float v = o_acc[n][i] / lrow[i];
      AOb[((size_t)b * 2048 + qr) * 768 + h * 64 + d] = f2bf(v);
    }
}

// ---------------- launch ----------------
extern "C" void kernel_launch(void* const* d_in, const int* in_sizes, int n_in,
                              void* d_out, int out_size, void* d_ws, size_t ws_size,
                              hipStream_t stream) {
  const float* x = (const float*)d_in[0];
  const float* wq = (const float*)d_in[1];
  const float* wk = (const float*)d_in[2];
  const float* wv = (const float*)d_in[3];
  const float* wo = (const float*)d_in[4];
  float* out = (float*)d_out;

  char* ws = (char*)d_ws;
  u16* xb   = (u16*)(ws);                 // [8192][768]
  u16* wqkv = (u16*)(ws + 12582912);      // [2304][768] rows: wq, wk, wv
  u16* wob  = (u16*)(ws + 16121856);      // [768][768]
  u16* Qb   = (u16*)(ws + 17301504);      // [48][2048][64]
  u16* Kb   = (u16*)(ws + 29884416);
  u16* Vb   = (u16*)(ws + 42467328);
  u16* AOb  = (u16*)(ws + 55050240);      // [8192][768]

  convert_kernel<<<6144, 256, 0, stream>>>(x, xb, 1572864);
  convert_kernel<<<576, 256, 0, stream>>>(wq, wqkv, 147456);
  convert_kernel<<<576, 256, 0, stream>>>(wk, wqkv + 589824, 147456);
  convert_kernel<<<576, 256, 0, stream>>>(wv, wqkv + 1179648, 147456);
  convert_kernel<<<576, 256, 0, stream>>>(wo, wob, 147456);

  gemm_bt<0><<<64 * 18, 256, 0, stream>>>(xb, wqkv, Qb, Kb, Vb, nullptr);
  attn_kernel<<<48 * 32, 256, 0, stream>>>(Qb, Kb, Vb, AOb);
  gemm_bt<1><<<64 * 6, 256, 0, stream>>>(AOb, wob, nullptr, nullptr, nullptr, out);
}

// Round 2
// 204.986 us; speedup vs baseline: 1.3284x; 1.3284x over previous
//
#include <hip/hip_runtime.h>
#include <stdint.h>

typedef unsigned short u16;
typedef __attribute__((ext_vector_type(8))) short short8;
typedef __attribute__((ext_vector_type(4))) float f32x4;

#define MFMA16(a, b, c) __builtin_amdgcn_mfma_f32_16x16x32_bf16(a, b, c, 0, 0, 0)

__device__ __forceinline__ void async16(void* lds, const void* g) {
  __builtin_amdgcn_global_load_lds(
      (const __attribute__((address_space(1))) void*)g,
      (__attribute__((address_space(3))) void*)lds, 16, 0, 0);
}

__device__ __forceinline__ u16 f2bf(float f) {
  unsigned u = __float_as_uint(f);
  u += 0x7FFF + ((u >> 16) & 1);
  return (u16)(u >> 16);
}

// ---------------- fp32 -> bf16 conversion ----------------
__global__ void convert_kernel(const float* __restrict__ src, u16* __restrict__ dst, int n4) {
  int i = blockIdx.x * 256 + threadIdx.x;
  if (i >= n4) return;
  float4 v = ((const float4*)src)[i];
  u16 o0 = f2bf(v.x), o1 = f2bf(v.y), o2 = f2bf(v.z), o3 = f2bf(v.w);
  unsigned lo = (unsigned)o0 | ((unsigned)o1 << 16);
  unsigned hi = (unsigned)o2 | ((unsigned)o3 << 16);
  ((uint2*)dst)[i] = make_uint2(lo, hi);
}

// ---------------- GEMM: C[m,n] = sum_k A[m,k] * Bw[n,k]  (both bf16, K=768) ----
// MODE 0: N=2304 (QKV fused). Q,K scatter [48][2048][64]; V scatter TRANSPOSED [48][64][2048].
// MODE 1: N=768, plain fp32 row-major output
template <int MODE>
__global__ __launch_bounds__(256) void gemm_bt(const u16* __restrict__ A,
                                               const u16* __restrict__ Bw,
                                               u16* __restrict__ Qb, u16* __restrict__ Kb,
                                               u16* __restrict__ Vb, float* __restrict__ Out) {
  __shared__ __align__(16) u16 As[128 * 32];
  __shared__ __align__(16) u16 Bs[128 * 32];
  const int bm = blockIdx.x & 63;   // 64 M-tiles
  const int bn = blockIdx.x >> 6;
  const int tid = threadIdx.x;
  const int wave = tid >> 6, lane = tid & 63;
  const int arow = lane & 15, kg = lane >> 4;
  const int wr = wave >> 1, wc = wave & 1;

  const int o = tid * 16;
  const int rowS = o >> 6;     // 64B rows (BK=32 bf16)
  const int cbS = o & 63;
  const char* gA0 = (const char*)A + (size_t)(bm * 128 + rowS) * 1536 + cbS;
  const char* gA1 = gA0 + (size_t)64 * 1536;
  const char* gB0 = (const char*)Bw + (size_t)(bn * 128 + rowS) * 1536 + cbS;
  const char* gB1 = gB0 + (size_t)64 * 1536;
  char* lA = (char*)As + wave * 1024;
  char* lB = (char*)Bs + wave * 1024;

  f32x4 acc[4][4];
#pragma unroll
  for (int m = 0; m < 4; ++m)
#pragma unroll
    for (int n = 0; n < 4; ++n) acc[m][n] = (f32x4)(0.0f);

  for (int kk = 0; kk < 24; ++kk) {
    async16(lA, gA0);
    async16(lA + 4096, gA1);
    async16(lB, gB0);
    async16(lB + 4096, gB1);
    gA0 += 64; gA1 += 64; gB0 += 64; gB1 += 64;
    __syncthreads();
    short8 av[4], bv[4];
#pragma unroll
    for (int m = 0; m < 4; ++m)
      av[m] = *(const short8*)(As + (wr * 64 + m * 16 + arow) * 32 + kg * 8);
#pragma unroll
    for (int n = 0; n < 4; ++n)
      bv[n] = *(const short8*)(Bs + (wc * 64 + n * 16 + arow) * 32 + kg * 8);
#pragma unroll
    for (int m = 0; m < 4; ++m)
#pragma unroll
      for (int n = 0; n < 4; ++n) acc[m][n] = MFMA16(av[m], bv[n], acc[m][n]);
    __syncthreads();
  }

#pragma unroll
  for (int m = 0; m < 4; ++m) {
    const int rbase = bm * 128 + wr * 64 + m * 16 + kg * 4;
#pragma unroll
    for (int n = 0; n < 4; ++n) {
      const int c = bn * 128 + wc * 64 + n * 16 + arow;
#pragma unroll
      for (int i = 0; i < 4; ++i) {
        float v = acc[m][n][i];
        int rr = rbase + i;
        if (MODE == 0) {
          int which = c / 768;
          int hc = c - which * 768;
          int h = hc >> 6, d = hc & 63;
          int b = rr >> 11, s = rr & 2047;
          size_t bh = (size_t)(b * 12 + h);
          if (which == 0) {
            Qb[(bh * 2048 + s) * 64 + d] = f2bf(v);
          } else if (which == 1) {
            Kb[(bh * 2048 + s) * 64 + d] = f2bf(v);
          } else {
            // V transposed: [bh][d][s]
            Vb[(bh * 64 + d) * 2048 + s] = f2bf(v);
          }
        } else {
          Out[(size_t)rr * 768 + c] = v;
        }
      }
    }
  }
}

// ---------------- causal flash attention ----------------
// grid: 48 head-batches * 32 Q-tiles; block 256 (4 waves, 16 q-rows each)
// K staged [k][d] swizzled; V staged pre-transposed [d][k] swizzled; both
// double-buffered with global_load_lds prefetch (T3 minimal 2-phase).
__global__ __launch_bounds__(256) void attn_kernel(const u16* __restrict__ Qb,
                                                   const u16* __restrict__ Kb,
                                                   const u16* __restrict__ Vb,  // [bh][64][2048]
                                                   u16* __restrict__ AOb) {
  __shared__ __align__(16) u16 Ks[2][64 * 64];   // K tiles, XOR-swizzled 128B rows
  __shared__ __align__(16) u16 Vt[2][64 * 64];   // V^T tiles [d][k], XOR-swizzled
  __shared__ __align__(16) u16 Ps[4][16 * 64];   // per-wave P, XOR-swizzled

  const int bid = blockIdx.x;
  // heavy-first (LPT): large qt dispatched first
  const int qt = 31 - (bid / 48);
  const int bh = bid % 48;
  const int tid = threadIdx.x, wave = tid >> 6, lane = tid & 63;
  const int arow = lane & 15, kg = lane >> 4;
  const size_t hbase = (size_t)bh * (2048 * 64);
  const u16* Qh = Qb + hbase;
  const u16* Kh = Kb + hbase;
  const u16* Vh = Vb + hbase;
  const int q0 = qt * 64 + wave * 16;

  short8 qf[2];
#pragma unroll
  for (int ks = 0; ks < 2; ++ks)
    qf[ks] = *(const short8*)(Qh + (size_t)(q0 + arow) * 64 + ks * 32 + kg * 8);

  f32x4 o_acc[4];
  float mrow[4], lrow[4];
#pragma unroll
  for (int n = 0; n < 4; ++n) o_acc[n] = (f32x4)(0.0f);
#pragma unroll
  for (int i = 0; i < 4; ++i) { mrow[i] = -1e30f; lrow[i] = 0.0f; }

  // staging geometry: per-wave base (global_load_lds lane offset is implicit)
  const int o0 = tid * 16;
  const int r0 = o0 >> 7, cb0 = o0 & 127;   // 128B rows, rows 0..31
  const int r1 = r0 + 32;
  const int sw0 = cb0 ^ (((r0 ^ (r0 >> 3)) & 7) << 4);
  const int sw1 = cb0 ^ (((r1 ^ (r1 >> 3)) & 7) << 4);
  char* const KsB = (char*)Ks;
  char* const VtB = (char*)Vt;

  const int ktiles = qt + 1;

  auto stage = [&](int buf, int kt) {
    const char* kb = (const char*)Kh + (size_t)kt * 8192;   // 64 rows * 128B
    async16(KsB + buf * 8192 + wave * 1024,        kb + r0 * 128 + sw0);
    async16(KsB + buf * 8192 + wave * 1024 + 4096, kb + r1 * 128 + sw1);
    const char* vb = (const char*)Vh + (size_t)kt * 128;    // row d: stride 4096B
    async16(VtB + buf * 8192 + wave * 1024,        vb + (size_t)r0 * 4096 + sw0);
    async16(VtB + buf * 8192 + wave * 1024 + 4096, vb + (size_t)r1 * 4096 + sw1);
  };

  // prologue
  stage(0, 0);
  asm volatile("s_waitcnt vmcnt(0)" ::: "memory");
  __builtin_amdgcn_s_barrier();

  int cur = 0;
  for (int kt = 0; kt < ktiles; ++kt) {
    if (kt + 1 < ktiles) stage(cur ^ 1, kt + 1);

    const char* Kc = KsB + cur * 8192;
    const char* Vc = VtB + cur * 8192;

    // QK^T: S[q][kcol], A=Q frag, B=K rows (contiguous in d)
    f32x4 s_acc[4];
#pragma unroll
    for (int cg = 0; cg < 4; ++cg) s_acc[cg] = (f32x4)(0.0f);
#pragma unroll
    for (int cg = 0; cg < 4; ++cg) {
      int krow = cg * 16 + arow;
      int fsw = ((krow ^ (krow >> 3)) & 7) << 4;
#pragma unroll
      for (int ks = 0; ks < 2; ++ks) {
        short8 kf = *(const short8*)(Kc + (krow << 7) + ((ks * 64 + kg * 16) ^ fsw));
        s_acc[cg] = MFMA16(qf[ks], kf, s_acc[cg]);
      }
    }

    // online softmax (wave-parallel: rows over i/kg, cols over 16 lanes)
    const int kbase = kt * 64;
    const bool diag = (kt == ktiles - 1);  // only the diagonal tile needs masking
    float sv[4][4];
#pragma unroll
    for (int cg = 0; cg < 4; ++cg) {
      int kc = kbase + cg * 16 + arow;
#pragma unroll
      for (int i = 0; i < 4; ++i) {
        float s = s_acc[cg][i] * 0.125f;
        if (diag) {
          int qr = q0 + kg * 4 + i;
          s = (kc > qr) ? -1e30f : s;
        }
        sv[cg][i] = s;
      }
    }
    float rmax[4];
#pragma unroll
    for (int i = 0; i < 4; ++i)
      rmax[i] = fmaxf(fmaxf(sv[0][i], sv[1][i]), fmaxf(sv[2][i], sv[3][i]));
#pragma unroll
    for (int off = 1; off < 16; off <<= 1)
#pragma unroll
      for (int i = 0; i < 4; ++i) rmax[i] = fmaxf(rmax[i], __shfl_xor(rmax[i], off));

    // defer-max (T13): only rescale when the max actually grew past THR
    float growth = fmaxf(fmaxf(rmax[0] - mrow[0], rmax[1] - mrow[1]),
                         fmaxf(rmax[2] - mrow[2], rmax[3] - mrow[3]));
    if (!__all(growth <= 8.0f)) {
#pragma unroll
      for (int i = 0; i < 4; ++i) {
        float mnew = fmaxf(mrow[i], rmax[i]);
        float corr = __expf(mrow[i] - mnew);
        mrow[i] = mnew;
        lrow[i] *= corr;
#pragma unroll
        for (int n = 0; n < 4; ++n) o_acc[n][i] *= corr;
      }
    }

    float pvv[4][4];
    float rsum[4] = {0.f, 0.f, 0.f, 0.f};
#pragma unroll
    for (int cg = 0; cg < 4; ++cg)
#pragma unroll
      for (int i = 0; i < 4; ++i) {
        float p = __expf(sv[cg][i] - mrow[i]);
        pvv[cg][i] = p;
        rsum[i] += p;
      }
#pragma unroll
    for (int off = 1; off < 16; off <<= 1)
#pragma unroll
      for (int i = 0; i < 4; ++i) rsum[i] += __shfl_xor(rsum[i], off);
#pragma unroll
    for (int i = 0; i < 4; ++i) lrow[i] += rsum[i];

    // write P (bf16) to per-wave LDS, swizzled
    u16* Pw = &Ps[wave][0];
#pragma unroll
    for (int cg = 0; cg < 4; ++cg)
#pragma unroll
      for (int i = 0; i < 4; ++i) {
        int r = kg * 4 + i;
        int off = (r << 7) + (((cg * 16 + arow) * 2) ^ (((r ^ (r >> 3)) & 7) << 4));
        *(u16*)((char*)Pw + off) = f2bf(pvv[cg][i]);
      }

    // PV: A = P [16q x 64k], B = V^T rows (contiguous in k)
#pragma unroll
    for (int ks = 0; ks < 2; ++ks) {
      int aoff = (arow << 7) + (((ks * 32 + kg * 8) * 2) ^ (((arow ^ (arow >> 3)) & 7) << 4));
      short8 pa = *(const short8*)((char*)Pw + aoff);
#pragma unroll
      for (int n = 0; n < 4; ++n) {
        int vrow = n * 16 + arow;
        int boff = (vrow << 7) + ((ks * 64 + kg * 16) ^ (((vrow ^ (vrow >> 3)) & 7) << 4));
        short8 vb = *(const short8*)(Vc + boff);
        o_acc[n] = MFMA16(pa, vb, o_acc[n]);
      }
    }

    // drain the prefetch (it had all of compute to land), then flip buffers
    asm volatile("s_waitcnt vmcnt(0)" ::: "memory");
    __builtin_amdgcn_s_barrier();
    cur ^= 1;
  }

  // epilogue: normalize and store attn_out bf16 in [B][S][H*64] layout
  const int b = bh / 12, h = bh - b * 12;
#pragma unroll
  for (int n = 0; n < 4; ++n)
#pragma unroll
    for (int i = 0; i < 4; ++i) {
      int qr = q0 + kg * 4 + i;
      int d = n * 16 + arow;
      float v = o_acc[n][i] / lrow[i];
      AOb[((size_t)b * 2048 + qr) * 768 + h * 64 + d] = f2bf(v);
    }
}

// ---------------- launch ----------------
extern "C" void kernel_launch(void* const* d_in, const int* in_sizes, int n_in,
                              void* d_out, int out_size, void* d_ws, size_t ws_size,
                              hipStream_t stream) {
  const float* x = (const float*)d_in[0];
  const float* wq = (const float*)d_in[1];
  const float* wk = (const float*)d_in[2];
  const float* wv = (const float*)d_in[3];
  const float* wo = (const float*)d_in[4];
  float* out = (float*)d_out;

  char* ws = (char*)d_ws;
  u16* xb   = (u16*)(ws);                 // [8192][768]
  u16* wqkv = (u16*)(ws + 12582912);      // [2304][768] rows: wq, wk, wv
  u16* wob  = (u16*)(ws + 16121856);      // [768][768]
  u16* Qb   = (u16*)(ws + 17301504);      // [48][2048][64]
  u16* Kb   = (u16*)(ws + 29884416);      // [48][2048][64]
  u16* Vb   = (u16*)(ws + 42467328);      // [48][64][2048]  (transposed)
  u16* AOb  = (u16*)(ws + 55050240);      // [8192][768]

  convert_kernel<<<6144, 256, 0, stream>>>(x, xb, 1572864);
  convert_kernel<<<576, 256, 0, stream>>>(wq, wqkv, 147456);
  convert_kernel<<<576, 256, 0, stream>>>(wk, wqkv + 589824, 147456);
  convert_kernel<<<576, 256, 0, stream>>>(wv, wqkv + 1179648, 147456);
  convert_kernel<<<576, 256, 0, stream>>>(wo, wob, 147456);

  gemm_bt<0><<<64 * 18, 256, 0, stream>>>(xb, wqkv, Qb, Kb, Vb, nullptr);
  attn_kernel<<<48 * 32, 256, 0, stream>>>(Qb, Kb, Vb, AOb);
  gemm_bt<1><<<64 * 6, 256, 0, stream>>>(AOb, wob, nullptr, nullptr, nullptr, out);
}

// Round 4
// 153.083 us; speedup vs baseline: 1.7788x; 1.3391x over previous
//
#include <hip/hip_runtime.h>
#include <stdint.h>

typedef unsigned short u16;
typedef __attribute__((ext_vector_type(8))) short short8;
typedef __attribute__((ext_vector_type(4))) short s16x4;
typedef __attribute__((ext_vector_type(4))) float f32x4;
typedef __attribute__((ext_vector_type(2))) unsigned uint2v;

#define MFMA16(a, b, c) __builtin_amdgcn_mfma_f32_16x16x32_bf16(a, b, c, 0, 0, 0)

// PV uses K=16 bf16 MFMA: B-operand k-layout (kg*4+i) matches swapped-QK P layout.
#if __has_builtin(__builtin_amdgcn_mfma_f32_16x16x16bf16_1k)
__device__ __forceinline__ f32x4 pv_mfma(s16x4 a, s16x4 b, f32x4 c) {
  return __builtin_amdgcn_mfma_f32_16x16x16bf16_1k(a, b, c, 0, 0, 0);
}
#else
__device__ __forceinline__ f32x4 pv_mfma(s16x4 a, s16x4 b, f32x4 c) {
  asm volatile("v_mfma_f32_16x16x16_bf16 %0, %1, %2, %0" : "+v"(c) : "v"(a), "v"(b));
  return c;
}
#endif

__device__ __forceinline__ void async16(void* lds, const void* g) {
  __builtin_amdgcn_global_load_lds(
      (const __attribute__((address_space(1))) void*)g,
      (__attribute__((address_space(3))) void*)lds, 16, 0, 0);
}

__device__ __forceinline__ u16 f2bf(float f) {
  unsigned u = __float_as_uint(f);
  u += 0x7FFF + ((u >> 16) & 1);
  return (u16)(u >> 16);
}

__device__ __forceinline__ unsigned cvtpk(float lo, float hi) {
  unsigned r;
  asm("v_cvt_pk_bf16_f32 %0, %1, %2" : "=v"(r) : "v"(lo), "v"(hi));
  return r;
}

// Q is pre-scaled by 1/sqrt(dh) * log2(e) so softmax runs in exp2 domain.
#define QSCALE 0.18033688011112042f
// Mask sentinel: far below any real score (|S| <= ~30) but small enough that
// no arithmetic on it can overflow. exp2f(MASKV - m) == 0 exactly.
#define MASKV -30000.0f

// ---------------- fp32 -> bf16 conversion ----------------
__global__ void convert_x(const float* __restrict__ src, u16* __restrict__ dst) {
  int i = blockIdx.x * 256 + threadIdx.x;
  float4 v = ((const float4*)src)[i];
  unsigned lo = (unsigned)f2bf(v.x) | ((unsigned)f2bf(v.y) << 16);
  unsigned hi = (unsigned)f2bf(v.z) | ((unsigned)f2bf(v.w) << 16);
  ((uint2*)dst)[i] = make_uint2(lo, hi);
}

__global__ void convert_w(const float* __restrict__ wq, const float* __restrict__ wk,
                          const float* __restrict__ wv, const float* __restrict__ wo,
                          u16* __restrict__ wqkv, u16* __restrict__ wob) {
  int i = blockIdx.x * 256 + threadIdx.x;   // [0, 589824)
  int wsel = i / 147456;
  int r = i - wsel * 147456;
  const float* s = (wsel == 0) ? wq : (wsel == 1) ? wk : (wsel == 2) ? wv : wo;
  float4 v = ((const float4*)s)[r];
  unsigned lo = (unsigned)f2bf(v.x) | ((unsigned)f2bf(v.y) << 16);
  unsigned hi = (unsigned)f2bf(v.z) | ((unsigned)f2bf(v.w) << 16);
  uint2 w = make_uint2(lo, hi);
  if (wsel < 3) ((uint2*)wqkv)[wsel * 147456 + r] = w;
  else ((uint2*)wob)[r] = w;
}

// ---------------- GEMM: C[m,n] = sum_k A[m,k] * Bw[n,k]  (both bf16, K=768) ----
// MODE 0: N=2304 (QKV fused). Q (scaled by QSCALE), K scatter [48][2048][64];
//         V scatter TRANSPOSED [48][64][2048].
// MODE 1: N=768, plain fp32 row-major output
template <int MODE>
__global__ __launch_bounds__(256) void gemm_bt(const u16* __restrict__ A,
                                               const u16* __restrict__ Bw,
                                               u16* __restrict__ Qb, u16* __restrict__ Kb,
                                               u16* __restrict__ Vb, float* __restrict__ Out) {
  __shared__ __align__(16) u16 As[128 * 32];
  __shared__ __align__(16) u16 Bs[128 * 32];
  const int bm = blockIdx.x & 63;   // 64 M-tiles
  const int bn = blockIdx.x >> 6;
  const int tid = threadIdx.x;
  const int wave = tid >> 6, lane = tid & 63;
  const int arow = lane & 15, kg = lane >> 4;
  const int wr = wave >> 1, wc = wave & 1;

  const int o = tid * 16;
  const int rowS = o >> 6;     // 64B rows (BK=32 bf16)
  const int cbS = o & 63;
  const char* gA0 = (const char*)A + (size_t)(bm * 128 + rowS) * 1536 + cbS;
  const char* gA1 = gA0 + (size_t)64 * 1536;
  const char* gB0 = (const char*)Bw + (size_t)(bn * 128 + rowS) * 1536 + cbS;
  const char* gB1 = gB0 + (size_t)64 * 1536;
  char* lA = (char*)As + wave * 1024;
  char* lB = (char*)Bs + wave * 1024;

  f32x4 acc[4][4];
#pragma unroll
  for (int m = 0; m < 4; ++m)
#pragma unroll
    for (int n = 0; n < 4; ++n) acc[m][n] = (f32x4)(0.0f);

  for (int kk = 0; kk < 24; ++kk) {
    async16(lA, gA0);
    async16(lA + 4096, gA1);
    async16(lB, gB0);
    async16(lB + 4096, gB1);
    gA0 += 64; gA1 += 64; gB0 += 64; gB1 += 64;
    __syncthreads();
    short8 av[4], bv[4];
#pragma unroll
    for (int m = 0; m < 4; ++m)
      av[m] = *(const short8*)(As + (wr * 64 + m * 16 + arow) * 32 + kg * 8);
#pragma unroll
    for (int n = 0; n < 4; ++n)
      bv[n] = *(const short8*)(Bs + (wc * 64 + n * 16 + arow) * 32 + kg * 8);
#pragma unroll
    for (int m = 0; m < 4; ++m)
#pragma unroll
      for (int n = 0; n < 4; ++n) acc[m][n] = MFMA16(av[m], bv[n], acc[m][n]);
    __syncthreads();
  }

#pragma unroll
  for (int m = 0; m < 4; ++m) {
    const int rbase = bm * 128 + wr * 64 + m * 16 + kg * 4;
#pragma unroll
    for (int n = 0; n < 4; ++n) {
      const int c = bn * 128 + wc * 64 + n * 16 + arow;
#pragma unroll
      for (int i = 0; i < 4; ++i) {
        float v = acc[m][n][i];
        int rr = rbase + i;
        if (MODE == 0) {
          int which = c / 768;
          int hc = c - which * 768;
          int h = hc >> 6, d = hc & 63;
          int b = rr >> 11, s = rr & 2047;
          size_t bh = (size_t)(b * 12 + h);
          if (which == 0) {
            Qb[(bh * 2048 + s) * 64 + d] = f2bf(v * QSCALE);
          } else if (which == 1) {
            Kb[(bh * 2048 + s) * 64 + d] = f2bf(v);
          } else {
            Vb[(bh * 64 + d) * 2048 + s] = f2bf(v);   // V transposed [bh][d][s]
          }
        } else {
          Out[(size_t)rr * 768 + c] = v;
        }
      }
    }
  }
}

// ---------------- causal flash attention (swapped QK^T) ----------------
// grid: 48 head-batches * 32 Q-tiles; block 256 (4 waves, 16 q-rows each).
// S computed as mfma(K, Q): per lane q = q0+arow (ONE q), k = cg*16+kg*4+i.
// Softmax: local tree + 2 shfl steps; m/l per-lane scalars; ALWAYS rescale
// (bounded-by-construction: corr<=1, p<=1, lrow<=2048 — no inf possible).
// PV via mfma 16x16x16 (K=16): P fragments are already in B-operand layout.
__global__ __launch_bounds__(256) void attn_kernel(const u16* __restrict__ Qb,
                                                   const u16* __restrict__ Kb,
                                                   const u16* __restrict__ Vb,  // [bh][64][2048]
                                                   u16* __restrict__ AOb) {
  __shared__ __align__(16) u16 Ks[2][64 * 64];   // K tiles, XOR-swizzled 128B rows
  __shared__ __align__(16) u16 Vt[2][64 * 64];   // V^T tiles [d][k], XOR-swizzled

  const int bid = blockIdx.x;
  const int qt = 31 - (bid / 48);    // heavy-first (LPT)
  const int bh = bid % 48;
  const int tid = threadIdx.x, wave = tid >> 6, lane = tid & 63;
  const int arow = lane & 15, kg = lane >> 4;
  const size_t hbase = (size_t)bh * (2048 * 64);
  const u16* Qh = Qb + hbase;
  const int q0 = qt * 64 + wave * 16;

  // Q fragment (B-operand): col q = q0+arow, 8 contiguous d per kg
  short8 qf[2];
#pragma unroll
  for (int ks = 0; ks < 2; ++ks)
    qf[ks] = *(const short8*)(Qh + (size_t)(q0 + arow) * 64 + ks * 32 + kg * 8);

  f32x4 o_acc[4];
#pragma unroll
  for (int n = 0; n < 4; ++n) o_acc[n] = (f32x4)(0.0f);
  float mrow = MASKV, lrow = 0.0f;

  // staging geometry (global_load_lds: wave-uniform LDS base + lane*16)
  const int o0 = tid * 16;
  const int r0 = o0 >> 7, cb0 = o0 & 127;   // rows 0..31
  const int r1 = r0 + 32;
  const int sw0 = cb0 ^ (((r0 ^ (r0 >> 3)) & 7) << 4);
  const int sw1 = cb0 ^ (((r1 ^ (r1 >> 3)) & 7) << 4);
  char* const KsB = (char*)Ks;
  char* const VtB = (char*)Vt;
  const int ldsw = wave * 1024;

  const char* gK0 = (const char*)(Kb + hbase) + r0 * 128 + sw0;
  const char* gK1 = (const char*)(Kb + hbase) + r1 * 128 + sw1;
  const char* gV0 = (const char*)(Vb + hbase) + (size_t)r0 * 4096 + sw0;
  const char* gV1 = (const char*)(Vb + hbase) + (size_t)r1 * 4096 + sw1;

  const int ktiles = qt + 1;

  auto stage = [&](int buf) {
    async16(KsB + buf * 8192 + ldsw,        gK0);
    async16(KsB + buf * 8192 + ldsw + 4096, gK1);
    async16(VtB + buf * 8192 + ldsw,        gV0);
    async16(VtB + buf * 8192 + ldsw + 4096, gV1);
    gK0 += 8192; gK1 += 8192; gV0 += 128; gV1 += 128;
  };

  stage(0);
  asm volatile("s_waitcnt vmcnt(0)" ::: "memory");
  __builtin_amdgcn_s_barrier();

  int cur = 0;
  for (int kt = 0; kt < ktiles; ++kt) {
    if (kt + 1 < ktiles) stage(cur ^ 1);

    const char* Kc = KsB + cur * 8192;
    const char* Vc = VtB + cur * 8192;

    // swapped QK^T: mfma(A=K, B=Q) -> S[k][q]; lane: q=q0+arow, k=cg*16+kg*4+i
    f32x4 s_acc[4];
#pragma unroll
    for (int cg = 0; cg < 4; ++cg) s_acc[cg] = (f32x4)(0.0f);
#pragma unroll
    for (int cg = 0; cg < 4; ++cg) {
      int krow = cg * 16 + arow;
      int fsw = ((krow ^ (krow >> 3)) & 7) << 4;
#pragma unroll
      for (int ks = 0; ks < 2; ++ks) {
        short8 kf = *(const short8*)(Kc + (krow << 7) + ((ks * 64 + kg * 16) ^ fsw));
        s_acc[cg] = MFMA16(kf, qf[ks], s_acc[cg]);
      }
    }

    // causal mask: only on the diagonal tile (kbase == qt*64)
    if (kt == ktiles - 1) {
      int rel = wave * 16 + arow - kg * 4;   // (q - kbase) - kg*4
#pragma unroll
      for (int cg = 0; cg < 4; ++cg)
#pragma unroll
        for (int i = 0; i < 4; ++i)
          s_acc[cg][i] = (cg * 16 + i > rel) ? MASKV : s_acc[cg][i];
    }

    // row max: 16 lane-local values + 2 shuffle steps (across kg groups)
    float rmax = s_acc[0][0];
#pragma unroll
    for (int cg = 0; cg < 4; ++cg)
#pragma unroll
      for (int i = 0; i < 4; ++i) rmax = fmaxf(rmax, s_acc[cg][i]);
    rmax = fmaxf(rmax, __shfl_xor(rmax, 16));
    rmax = fmaxf(rmax, __shfl_xor(rmax, 32));

    // always-rescale online softmax (corr in [0,1], p in [0,1] — bounded)
    {
      float mnew = fmaxf(mrow, rmax);
      float corr = exp2f(mrow - mnew);
      mrow = mnew;
      lrow *= corr;
#pragma unroll
      for (int n = 0; n < 4; ++n)
#pragma unroll
        for (int i = 0; i < 4; ++i) o_acc[n][i] *= corr;
    }

    float p[4][4];
    float rs = 0.0f;
#pragma unroll
    for (int cg = 0; cg < 4; ++cg)
#pragma unroll
      for (int i = 0; i < 4; ++i) {
        float e = exp2f(s_acc[cg][i] - mrow);
        p[cg][i] = e;
        rs += e;
      }
    rs += __shfl_xor(rs, 16);
    rs += __shfl_xor(rs, 32);
    lrow += rs;

    // pack P to bf16 (in-register, no LDS round-trip)
    s16x4 pb[4];
#pragma unroll
    for (int cg = 0; cg < 4; ++cg) {
      uint2v w;
      w.x = cvtpk(p[cg][0], p[cg][1]);
      w.y = cvtpk(p[cg][2], p[cg][3]);
      pb[cg] = __builtin_bit_cast(s16x4, w);
    }

    // PV: D[d][q] += V^T[d][k] * P[k][q] via 16x16x16 MFMA (K=16 per cg chunk)
#pragma unroll
    for (int n = 0; n < 4; ++n) {
      int vrow = n * 16 + arow;
      int f2 = ((vrow ^ (vrow >> 3)) & 7) << 4;
      const char* vb0 = Vc + (vrow << 7);
#pragma unroll
      for (int cg = 0; cg < 4; ++cg) {
        s16x4 va = *(const s16x4*)(vb0 + ((cg * 32 + kg * 8) ^ f2));
        o_acc[n] = pv_mfma(va, pb[cg], o_acc[n]);
      }
    }

    asm volatile("s_waitcnt vmcnt(0)" ::: "memory");
    __builtin_amdgcn_s_barrier();
    cur ^= 1;
  }

  // epilogue: normalize; store bf16 pairs. lane: q = q0+arow, d = n*16+kg*4+i
  const int b = bh / 12, h = bh - b * 12;
  float rinv = 1.0f / lrow;   // lrow >= 1 (row max contributes p = 1)
  size_t obase = ((size_t)b * 2048 + q0 + arow) * 768 + h * 64 + kg * 4;
#pragma unroll
  for (int n = 0; n < 4; ++n) {
#pragma unroll
    for (int t = 0; t < 2; ++t) {
      unsigned w = cvtpk(o_acc[n][2 * t] * rinv, o_acc[n][2 * t + 1] * rinv);
      *(unsigned*)(&AOb[obase + n * 16 + 2 * t]) = w;
    }
  }
}

// ---------------- launch ----------------
extern "C" void kernel_launch(void* const* d_in, const int* in_sizes, int n_in,
                              void* d_out, int out_size, void* d_ws, size_t ws_size,
                              hipStream_t stream) {
  const float* x = (const float*)d_in[0];
  const float* wq = (const float*)d_in[1];
  const float* wk = (const float*)d_in[2];
  const float* wv = (const float*)d_in[3];
  const float* wo = (const float*)d_in[4];
  float* out = (float*)d_out;

  char* ws = (char*)d_ws;
  u16* xb   = (u16*)(ws);                 // [8192][768]
  u16* wqkv = (u16*)(ws + 12582912);      // [2304][768] rows: wq, wk, wv
  u16* wob  = (u16*)(ws + 16121856);      // [768][768]
  u16* Qb   = (u16*)(ws + 17301504);      // [48][2048][64]  (pre-scaled)
  u16* Kb   = (u16*)(ws + 29884416);      // [48][2048][64]
  u16* Vb   = (u16*)(ws + 42467328);      // [48][64][2048]  (transposed)
  u16* AOb  = (u16*)(ws + 55050240);      // [8192][768]

  convert_x<<<6144, 256, 0, stream>>>(x, xb);
  convert_w<<<2304, 256, 0, stream>>>(wq, wk, wv, wo, wqkv, wob);

  gemm_bt<0><<<64 * 18, 256, 0, stream>>>(xb, wqkv, Qb, Kb, Vb, nullptr);
  attn_kernel<<<48 * 32, 256, 0, stream>>>(Qb, Kb, Vb, AOb);
  gemm_bt<1><<<64 * 6, 256, 0, stream>>>(AOb, wob, nullptr, nullptr, nullptr, out);
}

// Round 5
// 140.576 us; speedup vs baseline: 1.9371x; 1.0890x over previous
//
#include <hip/hip_runtime.h>
#include <stdint.h>

typedef unsigned short u16;
typedef __attribute__((ext_vector_type(8))) short short8;
typedef __attribute__((ext_vector_type(4))) short s16x4;
typedef __attribute__((ext_vector_type(4))) float f32x4;
typedef __attribute__((ext_vector_type(2))) unsigned uint2v;

#define MFMA16(a, b, c) __builtin_amdgcn_mfma_f32_16x16x32_bf16(a, b, c, 0, 0, 0)

// PV uses K=16 bf16 MFMA: B-operand k-layout (kg*4+i) matches swapped-QK P layout.
#if __has_builtin(__builtin_amdgcn_mfma_f32_16x16x16bf16_1k)
__device__ __forceinline__ f32x4 pv_mfma(s16x4 a, s16x4 b, f32x4 c) {
  return __builtin_amdgcn_mfma_f32_16x16x16bf16_1k(a, b, c, 0, 0, 0);
}
#else
__device__ __forceinline__ f32x4 pv_mfma(s16x4 a, s16x4 b, f32x4 c) {
  asm volatile("v_mfma_f32_16x16x16_bf16 %0, %1, %2, %0" : "+v"(c) : "v"(a), "v"(b));
  return c;
}
#endif

__device__ __forceinline__ void async16(void* lds, const void* g) {
  __builtin_amdgcn_global_load_lds(
      (const __attribute__((address_space(1))) void*)g,
      (__attribute__((address_space(3))) void*)lds, 16, 0, 0);
}

__device__ __forceinline__ u16 f2bf(float f) {
  unsigned u = __float_as_uint(f);
  u += 0x7FFF + ((u >> 16) & 1);
  return (u16)(u >> 16);
}

__device__ __forceinline__ unsigned cvtpk(float lo, float hi) {
  unsigned r;
  asm("v_cvt_pk_bf16_f32 %0, %1, %2" : "=v"(r) : "v"(lo), "v"(hi));
  return r;
}

// Q is pre-scaled by 1/sqrt(dh) * log2(e) so softmax runs in exp2 domain.
#define QSCALE 0.18033688011112042f
// Mask sentinel: far below any real score (|S| <= ~30) but small enough that
// no arithmetic on it can overflow. exp2f(MASKV - m) == 0 exactly.
#define MASKV -30000.0f

// ---------------- fp32 -> bf16 conversion ----------------
__global__ void convert_x(const float* __restrict__ src, u16* __restrict__ dst) {
  int i = blockIdx.x * 256 + threadIdx.x;
  float4 v = ((const float4*)src)[i];
  unsigned lo = (unsigned)f2bf(v.x) | ((unsigned)f2bf(v.y) << 16);
  unsigned hi = (unsigned)f2bf(v.z) | ((unsigned)f2bf(v.w) << 16);
  ((uint2*)dst)[i] = make_uint2(lo, hi);
}

__global__ void convert_w(const float* __restrict__ wq, const float* __restrict__ wk,
                          const float* __restrict__ wv, const float* __restrict__ wo,
                          u16* __restrict__ wqkv, u16* __restrict__ wob) {
  int i = blockIdx.x * 256 + threadIdx.x;   // [0, 589824)
  int wsel = i / 147456;
  int r = i - wsel * 147456;
  const float* s = (wsel == 0) ? wq : (wsel == 1) ? wk : (wsel == 2) ? wv : wo;
  float4 v = ((const float4*)s)[r];
  unsigned lo = (unsigned)f2bf(v.x) | ((unsigned)f2bf(v.y) << 16);
  unsigned hi = (unsigned)f2bf(v.z) | ((unsigned)f2bf(v.w) << 16);
  uint2 w = make_uint2(lo, hi);
  if (wsel < 3) ((uint2*)wqkv)[wsel * 147456 + r] = w;
  else ((uint2*)wob)[r] = w;
}

// ---------------- GEMM: C[m,n] = sum_k A[m,k] * Bw[n,k]  (both bf16, K=768) ----
// 128x128 tile, BK=32, double-buffered LDS with global_load_lds prefetch
// (T3 minimal 2-phase: stage(next) issued BEFORE compute(cur), one barrier/iter).
// MODE 0: N=2304 (QKV fused). Q (scaled by QSCALE), K scatter [48][2048][64];
//         V scatter TRANSPOSED [48][64][2048]. `which` is block-uniform (768=6*128).
// MODE 1: N=768, plain fp32 row-major output
template <int MODE>
__global__ __launch_bounds__(256) void gemm_bt(const u16* __restrict__ A,
                                               const u16* __restrict__ Bw,
                                               u16* __restrict__ Qb, u16* __restrict__ Kb,
                                               u16* __restrict__ Vb, float* __restrict__ Out) {
  __shared__ __align__(16) u16 As[2][128 * 32];
  __shared__ __align__(16) u16 Bs[2][128 * 32];
  const int bm = blockIdx.x & 63;   // 64 M-tiles
  const int bn = blockIdx.x >> 6;
  const int tid = threadIdx.x;
  const int wave = tid >> 6, lane = tid & 63;
  const int arow = lane & 15, kg = lane >> 4;
  const int wr = wave >> 1, wc = wave & 1;

  const int o = tid * 16;
  const int rowS = o >> 6;     // 64B rows (BK=32 bf16)
  const int cbS = o & 63;
  const char* gA0 = (const char*)A + (size_t)(bm * 128 + rowS) * 1536 + cbS;
  const char* gA1 = gA0 + (size_t)64 * 1536;
  const char* gB0 = (const char*)Bw + (size_t)(bn * 128 + rowS) * 1536 + cbS;
  const char* gB1 = gB0 + (size_t)64 * 1536;
  const int ldsw = wave * 1024;

  f32x4 acc[4][4];
#pragma unroll
  for (int m = 0; m < 4; ++m)
#pragma unroll
    for (int n = 0; n < 4; ++n) acc[m][n] = (f32x4)(0.0f);

  auto stage = [&](int buf) {
    async16((char*)As + buf * 8192 + ldsw,        gA0);
    async16((char*)As + buf * 8192 + ldsw + 4096, gA1);
    async16((char*)Bs + buf * 8192 + ldsw,        gB0);
    async16((char*)Bs + buf * 8192 + ldsw + 4096, gB1);
    gA0 += 64; gA1 += 64; gB0 += 64; gB1 += 64;
  };

  stage(0);
  asm volatile("s_waitcnt vmcnt(0)" ::: "memory");
  __builtin_amdgcn_s_barrier();

  int cur = 0;
  for (int kk = 0; kk < 24; ++kk) {
    if (kk + 1 < 24) stage(cur ^ 1);   // prefetch next K-step (hides under compute)

    const char* Ac = (const char*)As + cur * 8192;
    const char* Bc = (const char*)Bs + cur * 8192;
    short8 av[4], bv[4];
#pragma unroll
    for (int m = 0; m < 4; ++m)
      av[m] = *(const short8*)(Ac + (wr * 64 + m * 16 + arow) * 64 + kg * 16);
#pragma unroll
    for (int n = 0; n < 4; ++n)
      bv[n] = *(const short8*)(Bc + (wc * 64 + n * 16 + arow) * 64 + kg * 16);
#pragma unroll
    for (int m = 0; m < 4; ++m)
#pragma unroll
      for (int n = 0; n < 4; ++n) acc[m][n] = MFMA16(av[m], bv[n], acc[m][n]);

    asm volatile("s_waitcnt vmcnt(0)" ::: "memory");
    __builtin_amdgcn_s_barrier();
    cur ^= 1;
  }

  if (MODE == 0) {
    const int b = bm >> 4;                         // batch (block-uniform)
    const int sb = (bm & 15) * 128 + wr * 64 + kg * 4;  // + m*16 + i -> s
    const int which = bn / 6;                      // 0=Q 1=K 2=V (block-uniform)
    const int cbase = bn * 128 - which * 768 + wc * 64;
    if (which == 2) {
      // V transposed [bh][d][s]: 4 consecutive s per lane -> one 8B store
#pragma unroll
      for (int n = 0; n < 4; ++n) {
        int hc = cbase + n * 16 + arow;
        size_t rowb = ((size_t)(b * 12 + (hc >> 6)) * 64 + (hc & 63)) * 2048;
#pragma unroll
        for (int m = 0; m < 4; ++m) {
          uint2v w;
          w.x = cvtpk(acc[m][n][0], acc[m][n][1]);
          w.y = cvtpk(acc[m][n][2], acc[m][n][3]);
          *(uint2v*)(Vb + rowb + sb + m * 16) = w;
        }
      }
    } else {
      u16* const dst = which ? Kb : Qb;
      const float sc = which ? 1.0f : QSCALE;
#pragma unroll
      for (int n = 0; n < 4; ++n) {
        int hc = cbase + n * 16 + arow;
        size_t hb = ((size_t)(b * 12 + (hc >> 6)) * 2048) * 64 + (hc & 63);
#pragma unroll
        for (int m = 0; m < 4; ++m)
#pragma unroll
          for (int i = 0; i < 4; ++i)
            dst[hb + (size_t)(sb + m * 16 + i) * 64] = f2bf(acc[m][n][i] * sc);
      }
    }
  } else {
    const int rbase = bm * 128 + wr * 64 + kg * 4;
#pragma unroll
    for (int m = 0; m < 4; ++m)
#pragma unroll
      for (int n = 0; n < 4; ++n) {
        const int c = bn * 128 + wc * 64 + n * 16 + arow;
#pragma unroll
        for (int i = 0; i < 4; ++i)
          Out[(size_t)(rbase + m * 16 + i) * 768 + c] = acc[m][n][i];
      }
  }
}

// ---------------- causal flash attention (swapped QK^T) ----------------
// grid: 48 head-batches * 32 Q-tiles; block 256 (4 waves, 16 q-rows each).
// S computed as mfma(K, Q): per lane q = q0+arow (ONE q), k = cg*16+kg*4+i.
// Softmax: local tree + 2 shfl steps; m/l per-lane scalars; ALWAYS rescale
// (bounded-by-construction: corr<=1, p<=1, lrow<=2048 — no inf possible).
// PV via mfma 16x16x16 (K=16): P fragments are already in B-operand layout.
__global__ __launch_bounds__(256) void attn_kernel(const u16* __restrict__ Qb,
                                                   const u16* __restrict__ Kb,
                                                   const u16* __restrict__ Vb,  // [bh][64][2048]
                                                   u16* __restrict__ AOb) {
  __shared__ __align__(16) u16 Ks[2][64 * 64];   // K tiles, XOR-swizzled 128B rows
  __shared__ __align__(16) u16 Vt[2][64 * 64];   // V^T tiles [d][k], XOR-swizzled

  const int bid = blockIdx.x;
  const int qt = 31 - (bid / 48);    // heavy-first (LPT)
  const int bh = bid % 48;
  const int tid = threadIdx.x, wave = tid >> 6, lane = tid & 63;
  const int arow = lane & 15, kg = lane >> 4;
  const size_t hbase = (size_t)bh * (2048 * 64);
  const u16* Qh = Qb + hbase;
  const int q0 = qt * 64 + wave * 16;

  // Q fragment (B-operand): col q = q0+arow, 8 contiguous d per kg
  short8 qf[2];
#pragma unroll
  for (int ks = 0; ks < 2; ++ks)
    qf[ks] = *(const short8*)(Qh + (size_t)(q0 + arow) * 64 + ks * 32 + kg * 8);

  f32x4 o_acc[4];
#pragma unroll
  for (int n = 0; n < 4; ++n) o_acc[n] = (f32x4)(0.0f);
  float mrow = MASKV, lrow = 0.0f;

  // staging geometry (global_load_lds: wave-uniform LDS base + lane*16)
  const int o0 = tid * 16;
  const int r0 = o0 >> 7, cb0 = o0 & 127;   // rows 0..31
  const int r1 = r0 + 32;
  const int sw0 = cb0 ^ (((r0 ^ (r0 >> 3)) & 7) << 4);
  const int sw1 = cb0 ^ (((r1 ^ (r1 >> 3)) & 7) << 4);
  char* const KsB = (char*)Ks;
  char* const VtB = (char*)Vt;
  const int ldsw = wave * 1024;

  const char* gK0 = (const char*)(Kb + hbase) + r0 * 128 + sw0;
  const char* gK1 = (const char*)(Kb + hbase) + r1 * 128 + sw1;
  const char* gV0 = (const char*)(Vb + hbase) + (size_t)r0 * 4096 + sw0;
  const char* gV1 = (const char*)(Vb + hbase) + (size_t)r1 * 4096 + sw1;

  const int ktiles = qt + 1;

  auto stage = [&](int buf) {
    async16(KsB + buf * 8192 + ldsw,        gK0);
    async16(KsB + buf * 8192 + ldsw + 4096, gK1);
    async16(VtB + buf * 8192 + ldsw,        gV0);
    async16(VtB + buf * 8192 + ldsw + 4096, gV1);
    gK0 += 8192; gK1 += 8192; gV0 += 128; gV1 += 128;
  };

  stage(0);
  asm volatile("s_waitcnt vmcnt(0)" ::: "memory");
  __builtin_amdgcn_s_barrier();

  int cur = 0;
  for (int kt = 0; kt < ktiles; ++kt) {
    if (kt + 1 < ktiles) stage(cur ^ 1);

    const char* Kc = KsB + cur * 8192;
    const char* Vc = VtB + cur * 8192;

    // swapped QK^T: mfma(A=K, B=Q) -> S[k][q]; lane: q=q0+arow, k=cg*16+kg*4+i
    f32x4 s_acc[4];
#pragma unroll
    for (int cg = 0; cg < 4; ++cg) s_acc[cg] = (f32x4)(0.0f);
#pragma unroll
    for (int cg = 0; cg < 4; ++cg) {
      int krow = cg * 16 + arow;
      int fsw = ((krow ^ (krow >> 3)) & 7) << 4;
#pragma unroll
      for (int ks = 0; ks < 2; ++ks) {
        short8 kf = *(const short8*)(Kc + (krow << 7) + ((ks * 64 + kg * 16) ^ fsw));
        s_acc[cg] = MFMA16(kf, qf[ks], s_acc[cg]);
      }
    }

    // causal mask: only on the diagonal tile (kbase == qt*64)
    if (kt == ktiles - 1) {
      int rel = wave * 16 + arow - kg * 4;   // (q - kbase) - kg*4
#pragma unroll
      for (int cg = 0; cg < 4; ++cg)
#pragma unroll
        for (int i = 0; i < 4; ++i)
          s_acc[cg][i] = (cg * 16 + i > rel) ? MASKV : s_acc[cg][i];
    }

    // row max: 16 lane-local values + 2 shuffle steps (across kg groups)
    float rmax = s_acc[0][0];
#pragma unroll
    for (int cg = 0; cg < 4; ++cg)
#pragma unroll
      for (int i = 0; i < 4; ++i) rmax = fmaxf(rmax, s_acc[cg][i]);
    rmax = fmaxf(rmax, __shfl_xor(rmax, 16));
    rmax = fmaxf(rmax, __shfl_xor(rmax, 32));

    // always-rescale online softmax (corr in [0,1], p in [0,1] — bounded)
    {
      float mnew = fmaxf(mrow, rmax);
      float corr = exp2f(mrow - mnew);
      mrow = mnew;
      lrow *= corr;
#pragma unroll
      for (int n = 0; n < 4; ++n)
#pragma unroll
        for (int i = 0; i < 4; ++i) o_acc[n][i] *= corr;
    }

    float p[4][4];
    float rs = 0.0f;
#pragma unroll
    for (int cg = 0; cg < 4; ++cg)
#pragma unroll
      for (int i = 0; i < 4; ++i) {
        float e = exp2f(s_acc[cg][i] - mrow);
        p[cg][i] = e;
        rs += e;
      }
    rs += __shfl_xor(rs, 16);
    rs += __shfl_xor(rs, 32);
    lrow += rs;

    // pack P to bf16 (in-register, no LDS round-trip)
    s16x4 pb[4];
#pragma unroll
    for (int cg = 0; cg < 4; ++cg) {
      uint2v w;
      w.x = cvtpk(p[cg][0], p[cg][1]);
      w.y = cvtpk(p[cg][2], p[cg][3]);
      pb[cg] = __builtin_bit_cast(s16x4, w);
    }

    // PV: D[d][q] += V^T[d][k] * P[k][q] via 16x16x16 MFMA (K=16 per cg chunk)
#pragma unroll
    for (int n = 0; n < 4; ++n) {
      int vrow = n * 16 + arow;
      int f2 = ((vrow ^ (vrow >> 3)) & 7) << 4;
      const char* vb0 = Vc + (vrow << 7);
#pragma unroll
      for (int cg = 0; cg < 4; ++cg) {
        s16x4 va = *(const s16x4*)(vb0 + ((cg * 32 + kg * 8) ^ f2));
        o_acc[n] = pv_mfma(va, pb[cg], o_acc[n]);
      }
    }

    asm volatile("s_waitcnt vmcnt(0)" ::: "memory");
    __builtin_amdgcn_s_barrier();
    cur ^= 1;
  }

  // epilogue: normalize; store bf16 pairs. lane: q = q0+arow, d = n*16+kg*4+i
  const int b = bh / 12, h = bh - b * 12;
  float rinv = 1.0f / lrow;   // lrow >= 1 (row max contributes p = 1)
  size_t obase = ((size_t)b * 2048 + q0 + arow) * 768 + h * 64 + kg * 4;
#pragma unroll
  for (int n = 0; n < 4; ++n) {
#pragma unroll
    for (int t = 0; t < 2; ++t) {
      unsigned w = cvtpk(o_acc[n][2 * t] * rinv, o_acc[n][2 * t + 1] * rinv);
      *(unsigned*)(&AOb[obase + n * 16 + 2 * t]) = w;
    }
  }
}

// ---------------- launch ----------------
extern "C" void kernel_launch(void* const* d_in, const int* in_sizes, int n_in,
                              void* d_out, int out_size, void* d_ws, size_t ws_size,
                              hipStream_t stream) {
  const float* x = (const float*)d_in[0];
  const float* wq = (const float*)d_in[1];
  const float* wk = (const float*)d_in[2];
  const float* wv = (const float*)d_in[3];
  const float* wo = (const float*)d_in[4];
  float* out = (float*)d_out;

  char* ws = (char*)d_ws;
  u16* xb   = (u16*)(ws);                 // [8192][768]
  u16* wqkv = (u16*)(ws + 12582912);      // [2304][768] rows: wq, wk, wv
  u16* wob  = (u16*)(ws + 16121856);      // [768][768]
  u16* Qb   = (u16*)(ws + 17301504);      // [48][2048][64]  (pre-scaled)
  u16* Kb   = (u16*)(ws + 29884416);      // [48][2048][64]
  u16* Vb   = (u16*)(ws + 42467328);      // [48][64][2048]  (transposed)
  u16* AOb  = (u16*)(ws + 55050240);      // [8192][768]

  convert_x<<<6144, 256, 0, stream>>>(x, xb);
  convert_w<<<2304, 256, 0, stream>>>(wq, wk, wv, wo, wqkv, wob);

  gemm_bt<0><<<64 * 18, 256, 0, stream>>>(xb, wqkv, Qb, Kb, Vb, nullptr);
  attn_kernel<<<48 * 32, 256, 0, stream>>>(Qb, Kb, Vb, AOb);
  gemm_bt<1><<<64 * 6, 256, 0, stream>>>(AOb, wob, nullptr, nullptr, nullptr, out);
}